// Round 12
// baseline (123.273 us; speedup 1.0000x reference)
//
#include <hip/hip_runtime.h>

// CrossModalAttention  B=8, CQ=CKV=E=256, Nq=4096, Nkv=1024
// out = concat([C, (out_w@g_w@P) @ softmax(thetaC^T @ phiP / 16)^T], axis=1)

typedef __attribute__((ext_vector_type(8))) short short8;   // 8 bf16 raw
typedef __attribute__((ext_vector_type(16))) float f32x16;
typedef unsigned short ushort_t;

__device__ __forceinline__ unsigned short f2bf(float f) {
    unsigned int u = __float_as_uint(f);
    u += 0x7FFFu + ((u >> 16) & 1u);            // RNE
    return (unsigned short)(u >> 16);
}
__device__ __forceinline__ unsigned int pack2bf(float a, float b) {
    return (unsigned int)f2bf(a) | ((unsigned int)f2bf(b) << 16);
}
__device__ __forceinline__ void gload16(const ushort_t* g, ushort_t* l) {
    __builtin_amdgcn_global_load_lds(
        (const __attribute__((address_space(1))) unsigned int*)g,
        (__attribute__((address_space(3))) unsigned int*)l, 16, 0, 0);
}
__device__ __forceinline__ f32x16 zero16() {
    f32x16 z;
#pragma unroll
    for (int i = 0; i < 16; ++i) z[i] = 0.f;
    return z;
}

// ---------------- prep_w: weight chunk cvts + W2 (tiny, weights only) ----------------
__global__ __launch_bounds__(256) void prep_w(const float* __restrict__ thw,
                                              const float* __restrict__ phw,
                                              const float* __restrict__ ow,
                                              const float* __restrict__ gw,
                                              ushort_t* __restrict__ thc,
                                              ushort_t* __restrict__ phc,
                                              ushort_t* __restrict__ w2c) {
    int blk = blockIdx.x;
    int t = threadIdx.x;
    if (blk < 512) {
        int which = blk >> 8;
        int e = blk & 255, c = t;
        const float* src = which ? phw : thw;
        ushort_t* dst = which ? phc : thc;
        int idx = ((((e >> 5) * 16 + (c >> 4)) * 64 + ((c >> 3) & 1) * 32 + (e & 31)) << 3) + (c & 7);
        dst[idx] = f2bf(src[e * 256 + c]);
    } else {
        int c0 = (blk - 512) * 8;
        float acc[8] = {};
        for (int e = 0; e < 256; ++e) {
            float g = gw[e * 256 + t];
#pragma unroll
            for (int i = 0; i < 8; ++i) acc[i] += ow[(c0 + i) * 256 + e] * g;
        }
#pragma unroll
        for (int i = 0; i < 8; ++i) {
            int c = c0 + i, k = t;
            int idx = ((((c >> 5) * 16 + (k >> 4)) * 64 + ((k >> 3) & 1) * 32 + (c & 31)) << 3) + (k & 7);
            w2c[idx] = f2bf(acc[i]);
        }
    }
}

// ---------------- proj_all: fp32 X-slice -> LDS -> pack B-frags -> MFMA ----------------
__global__ __launch_bounds__(256, 2) void proj_all(const ushort_t* __restrict__ thc,
                                                   const ushort_t* __restrict__ phc,
                                                   const ushort_t* __restrict__ w2c,
                                                   const float* __restrict__ C,
                                                   const float* __restrict__ P,
                                                   ushort_t* __restrict__ thetaA,
                                                   ushort_t* __restrict__ phiA,
                                                   ushort_t* __restrict__ gVx) {
    __shared__ float Xs[256][68];
    int blk = blockIdx.x;
    int tid = threadIdx.x, lane = tid & 63, wid = tid >> 6;
    int l31 = lane & 31, lh = lane >> 5;
    const int wq = wid & 1, we = wid >> 1;

    int role, b, nt, N;
    const ushort_t* Wc;
    const float* Xg;
    ushort_t* outp;
    float scale = 1.f;
    if (blk < 512) {
        role = 0; b = blk & 7; nt = blk >> 3;
        Wc = thc; Xg = C + (size_t)b * 1048576; outp = thetaA + (size_t)b * 1048576;
        N = 4096; scale = 1.4426950408889634f / 16.0f;
    } else if (blk < 640) {
        int r = blk - 512; role = 1; b = r & 7; nt = r >> 3;
        Wc = phc; Xg = P + (size_t)b * 262144; outp = phiA + (size_t)b * 262144;
        N = 1024;
    } else {
        int r = blk - 640; role = 2; b = r & 7; nt = r >> 3;
        Wc = w2c; Xg = P + (size_t)b * 262144; outp = gVx + (size_t)b * 262144;
        N = 1024;
    }

    {
        const float* Xb = Xg + nt * 64;
#pragma unroll
        for (int i = 0; i < 16; ++i) {
            int idx = i * 256 + tid;
            int row = idx >> 4, c4 = (idx & 15) * 4;
            *(float4*)&Xs[row][c4] = *(const float4*)(Xb + (size_t)row * N + c4);
        }
    }
    __syncthreads();

    const int n0 = nt * 64 + wq * 32;
    const int ncr = (n0 >> 5) * 16;
    const int q = wq * 32 + l31;

    f32x16 o[4];
#pragma unroll
    for (int f = 0; f < 4; ++f) o[f] = zero16();

#pragma unroll
    for (int ks = 0; ks < 16; ++ks) {
        const int cb = ks * 16 + lh * 8;
        union PW { unsigned int u[4]; short8 v; } xw;
#pragma unroll
        for (int j = 0; j < 4; ++j)
            xw.u[j] = pack2bf(Xs[cb + 2 * j][q], Xs[cb + 2 * j + 1][q]);
#pragma unroll
        for (int f2 = 0; f2 < 4; ++f2) {
            int f = we * 4 + f2;
            short8 wf = *(const short8*)(Wc + ((size_t)(f * 16 + ks) * 64 + lane) * 8);
            o[f2] = __builtin_amdgcn_mfma_f32_32x32x16_bf16(wf, xw.v, o[f2], 0, 0, 0);
        }
    }

    if (role < 2) {
#pragma unroll
        for (int f2 = 0; f2 < 4; ++f2) {
            int f = we * 4 + f2;
#pragma unroll
            for (int rq = 0; rq < 4; ++rq) {
                uint2 st;
                st.x = pack2bf(o[f2][4 * rq + 0] * scale, o[f2][4 * rq + 1] * scale);
                st.y = pack2bf(o[f2][4 * rq + 2] * scale, o[f2][4 * rq + 3] * scale);
                size_t addr = ((size_t)(ncr + f * 2 + (rq >> 1)) * 64 + l31 + 32 * (rq & 1)) * 8 + 4 * lh;
                *(uint2*)(outp + addr) = st;
            }
        }
    } else {
        int kvq = (n0 >> 4) + (l31 >> 4);
        int lhw = 32 * ((l31 >> 3) & 1);
        int kl = l31 & 7;
#pragma unroll
        for (int f2 = 0; f2 < 4; ++f2) {
            int f = we * 4 + f2;
#pragma unroll
            for (int r2 = 0; r2 < 16; ++r2) {
                int crow = (r2 & 3) + 8 * (r2 >> 2) + 4 * lh;
                size_t addr = ((size_t)(f * 64 + kvq) * 64 + crow + lhw) * 8 + kl;
                outp[addr] = f2bf(o[f2][r2]);
            }
        }
    }
}

// ---------------- attn9: e-split waves (redundant QK), o[4], no merge epilogue --------
// 8 waves = 4 q-groups x 2 e-halves. Each wave: 32 q, full 1024 kv, PV for 128 e.
// kv-tile 64/iter, 16 iters. K/V 32 KB each, double-buffered (128 KB), staged 1 ahead.
__global__ __launch_bounds__(512, 2) void attn9(const ushort_t* __restrict__ thetaA,
                                                const ushort_t* __restrict__ phiA,
                                                const ushort_t* __restrict__ gVx,
                                                const float* __restrict__ Cf,
                                                float* __restrict__ out) {
    const int b = blockIdx.x & 7, qt = blockIdx.x >> 3;   // batch == XCD
    const int tid = threadIdx.x, lane = tid & 63, wid = tid >> 6;
    const int l31 = lane & 31, lh = lane >> 5;
    const int g = wid & 3, eh = wid >> 2;

    __shared__ __align__(16) ushort_t smem[65536];        // K: [2][16384]; V: 32768+[2][16384]

    const ushort_t* thA = thetaA + (size_t)b * 1048576;
    const ushort_t* phA = phiA + (size_t)b * 262144;
    const ushort_t* gVb = gVx + (size_t)b * 262144;

    // stage 64-kv tile j into buffer d; every wave issues exactly 8 gload16
    auto stage = [&](int j, int d) {
        if (wid < 4) {       // K: 32 KB contiguous (two 8 KB sub-tiles in chunk order)
            const ushort_t* src = phA + (size_t)j * 16384 + (size_t)wid * 4096 + lane * 8;
            ushort_t* dst = smem + d * 16384 + wid * 4096;
#pragma unroll
            for (int i = 0; i < 8; ++i) gload16(src + i * 512, dst + i * 512);
        } else {             // V: chunks (f, kvq = j*4 + jj)
            int w = wid - 4;
#pragma unroll
            for (int q2 = 0; q2 < 2; ++q2) {
                int f = w * 2 + q2;
#pragma unroll
                for (int jj = 0; jj < 4; ++jj) {
                    const ushort_t* src = gVb + ((size_t)(f * 64 + j * 4 + jj) * 64 + lane) * 8;
                    ushort_t* dst = smem + 32768 + d * 16384 + f * 2048 + jj * 512;
                    gload16(src, dst);
                }
            }
        }
    };

    stage(0, 0);

    // Q B-frags: 32 q per group, 16 k-steps
    short8 qf[16];
    {
        const int qcr = (qt * 4 + g) * 16;
#pragma unroll
        for (int ks = 0; ks < 16; ++ks)
            qf[ks] = *(const short8*)(thA + ((size_t)(qcr + ks) * 64 + lane) * 8);
    }

    f32x16 o[4];
#pragma unroll
    for (int f = 0; f < 4; ++f) o[f] = zero16();
    float rl = 0.f;

    // C-copy fold (spread over loop): row = it*16 + 2*wid + lh, col = qt*128 + l31*4
    const size_t cbase = (size_t)b * 1048576 + (size_t)qt * 128 + (size_t)l31 * 4;
    const size_t dofs = (size_t)b * 1048576;
    size_t cpo = 0;
    float4 cpv;

    for (int it = 0; it < 16; ++it) {
        asm volatile("s_waitcnt vmcnt(0)" ::: "memory");
        __builtin_amdgcn_s_barrier();
        __builtin_amdgcn_sched_barrier(0);
        if (it < 15) stage(it + 1, (it + 1) & 1);

        // C-copy: store prev slice, load this one
        if (it > 0) *(float4*)(out + cpo + dofs) = cpv;
        cpo = cbase + (size_t)(it * 16 + 2 * wid + lh) * 4096;
        cpv = *(const float4*)(Cf + cpo);

        const ushort_t* Kb = smem + (it & 1) * 16384;
        const ushort_t* Vb = smem + 32768 + (it & 1) * 16384 + eh * 8192;

        // ---- QK: S^T[64 kv][32 q], two kv-frags ----
        f32x16 s0 = zero16(), s1 = zero16();
#pragma unroll
        for (int ks = 0; ks < 16; ++ks) {
            short8 kf0 = *(const short8*)(Kb + (size_t)ks * 512 + lane * 8);
            short8 kf1 = *(const short8*)(Kb + 8192 + (size_t)ks * 512 + lane * 8);
            s0 = __builtin_amdgcn_mfma_f32_32x32x16_bf16(kf0, qf[ks], s0, 0, 0, 0);
            s1 = __builtin_amdgcn_mfma_f32_32x32x16_bf16(kf1, qf[ks], s1, 0, 0, 0);
        }

        // ---- no-max softmax: p = exp2(s), rl += sum (q = l31 per lane) ----
        float ps = 0.f;
#pragma unroll
        for (int r = 0; r < 16; ++r) {
            s0[r] = __builtin_amdgcn_exp2f(s0[r]);
            s1[r] = __builtin_amdgcn_exp2f(s1[r]);
            ps += s0[r] + s1[r];
        }
        ps += __shfl_xor(ps, 32);
        rl += ps;

        // ---- T12 x2: S-regs -> 4 PV B-frags via cvt_pk + permlane32_swap ----
        unsigned int a0 = pack2bf(s0[0], s0[1]),   b0 = pack2bf(s0[4], s0[5]);
        unsigned int a1 = pack2bf(s0[2], s0[3]),   b1 = pack2bf(s0[6], s0[7]);
        unsigned int a2 = pack2bf(s0[8], s0[9]),   b2 = pack2bf(s0[12], s0[13]);
        unsigned int a3 = pack2bf(s0[10], s0[11]), b3 = pack2bf(s0[14], s0[15]);
        asm volatile("v_permlane32_swap_b32 %0, %1" : "+v"(a0), "+v"(b0));
        asm volatile("v_permlane32_swap_b32 %0, %1" : "+v"(a1), "+v"(b1));
        asm volatile("v_permlane32_swap_b32 %0, %1" : "+v"(a2), "+v"(b2));
        asm volatile("v_permlane32_swap_b32 %0, %1" : "+v"(a3), "+v"(b3));
        unsigned int c0 = pack2bf(s1[0], s1[1]),   d0 = pack2bf(s1[4], s1[5]);
        unsigned int c1 = pack2bf(s1[2], s1[3]),   d1 = pack2bf(s1[6], s1[7]);
        unsigned int c2 = pack2bf(s1[8], s1[9]),   d2 = pack2bf(s1[12], s1[13]);
        unsigned int c3 = pack2bf(s1[10], s1[11]), d3 = pack2bf(s1[14], s1[15]);
        asm volatile("v_permlane32_swap_b32 %0, %1" : "+v"(c0), "+v"(d0));
        asm volatile("v_permlane32_swap_b32 %0, %1" : "+v"(c1), "+v"(d1));
        asm volatile("v_permlane32_swap_b32 %0, %1" : "+v"(c2), "+v"(d2));
        asm volatile("v_permlane32_swap_b32 %0, %1" : "+v"(c3), "+v"(d3));
        union PW { unsigned int u[4]; short8 v; };
        PW pw[4];
        pw[0].u[0] = a0; pw[0].u[1] = a1; pw[0].u[2] = b0; pw[0].u[3] = b1;
        pw[1].u[0] = a2; pw[1].u[1] = a3; pw[1].u[2] = b2; pw[1].u[3] = b3;
        pw[2].u[0] = c0; pw[2].u[1] = c1; pw[2].u[2] = d0; pw[2].u[3] = d1;
        pw[3].u[0] = c2; pw[3].u[1] = c3; pw[3].u[2] = d2; pw[3].u[3] = d3;

        // ---- PV: O^T[e-half][q] += V^T P, 4 k-steps x 4 e-frags ----
        __builtin_amdgcn_s_setprio(1);
#pragma unroll
        for (int ks2 = 0; ks2 < 4; ++ks2) {
            short8 pf = pw[ks2].v;
#pragma unroll
            for (int fl = 0; fl < 4; ++fl) {
                short8 vf = *(const short8*)(Vb + (size_t)fl * 2048 + ks2 * 512 + lane * 8);
                o[fl] = __builtin_amdgcn_mfma_f32_32x32x16_bf16(vf, pf, o[fl], 0, 0, 0);
            }
        }
        __builtin_amdgcn_s_setprio(0);
    }

    *(float4*)(out + cpo + dofs) = cpv;   // last copy slice

    // ---- epilogue: direct normalized store (no merge, disjoint e per wave) ----
    float inv = 1.f / rl;
    float* ob = out + (size_t)b * 2097152 + (size_t)256 * 4096 + qt * 128 + g * 32 + l31;
#pragma unroll
    for (int fl = 0; fl < 4; ++fl) {
#pragma unroll
        for (int r = 0; r < 16; ++r) {
            int e = eh * 128 + fl * 32 + (r & 3) + 8 * (r >> 2) + 4 * lh;
            ob[(size_t)e * 4096] = o[fl][r] * inv;
        }
    }
}

// ---------------- launch ----------------

extern "C" void kernel_launch(void* const* d_in, const int* in_sizes, int n_in,
                              void* d_out, int out_size, void* d_ws, size_t ws_size,
                              hipStream_t stream) {
    const float* C       = (const float*)d_in[0];
    const float* P       = (const float*)d_in[1];
    const float* theta_w = (const float*)d_in[2];
    const float* phi_w   = (const float*)d_in[3];
    const float* g_w     = (const float*)d_in[4];
    const float* out_w   = (const float*)d_in[5];
    float* out = (float*)d_out;

    ushort_t* ws = (ushort_t*)d_ws;
    ushort_t* thetaA = ws;                        // 8,388,608
    ushort_t* phiA   = ws + 8388608;              // 2,097,152
    ushort_t* gVx    = ws + 10485760;             // 2,097,152
    ushort_t* thWc   = ws + 12582912;             // 65,536
    ushort_t* phWc   = ws + 12648448;             // 65,536
    ushort_t* w2c    = ws + 12713984;             // 65,536

    prep_w<<<544, 256, 0, stream>>>(theta_w, phi_w, out_w, g_w, thWc, phWc, w2c);
    proj_all<<<768, 256, 0, stream>>>(thWc, phWc, w2c, C, P, thetaA, phiA, gVx);
    attn9<<<256, 512, 0, stream>>>(thetaA, phiA, gVx, C, out);
}